// Round 6
// baseline (83.290 us; speedup 1.0000x reference)
//
#include <hip/hip_runtime.h>
#include <math.h>

// Problem geometry (fixed by reference)
#define BATCH   4096
#define NVARS   1024
#define ROWS_P0 8192
#define ROWS_S1 4096
#define ROWS_P2 8192
#define ROWS_S3 2048

#define LOG2E 1.4426950408889634f
#define LN2   0.6931471805599453f

typedef _Float16 h2 __attribute__((ext_vector_type(2)));

__device__ __forceinline__ float log1mexp_f(float x) {
    // accurate log(1 - exp(x)) for x < 0 (Maechler 2012) — libm for precision near 0-
    if (x > -0.6931471805599453f) return logf(-expm1f(x));
    return log1pf(-expf(x));
}

__device__ __forceinline__ float fexp2(float x) { return __builtin_amdgcn_exp2f(x); }
__device__ __forceinline__ float flog2(float x) { return __builtin_amdgcn_logf(x); }

// Pack two positive f32 -> bf16x2 in one u32 via explicit RNE bit-twiddle.
// (Round-5 lesson: hand-written v_cvt_pk_bf16_f32 asm produced NaN — guide m240
// says don't hand-write cvt_pk. This is plain VALU, verifiable by inspection.)
__device__ __forceinline__ unsigned pk_bf16(float x, float y) {
    unsigned xb = __float_as_uint(x);
    unsigned yb = __float_as_uint(y);
    xb += 0x7FFFu + ((xb >> 16) & 1u);   // RNE round into bf16
    yb += 0x7FFFu + ((yb >> 16) & 1u);
    return (xb >> 16) | (yb & 0xFFFF0000u);
}
__device__ __forceinline__ float bf_lo(unsigned v) { return __uint_as_float(v << 16); }
__device__ __forceinline__ float bf_hi(unsigned v) { return __uint_as_float(v & 0xFFFF0000u); }

// ---------------- generic 32x32 tiled transpose: dst[c][r] = src[r][c] ----------------
__global__ __launch_bounds__(256) void transpose_kernel(const float* __restrict__ src,
                                                        float* __restrict__ dst,
                                                        int R, int C) {
    __shared__ float tile[32][33];
    int bx = blockIdx.x, by = blockIdx.y;    // bx tiles C, by tiles R
    int tx = threadIdx.x, ty = threadIdx.y;  // block (32, 8)
    int c = bx * 32 + tx;
#pragma unroll
    for (int i = 0; i < 4; ++i) {
        int r = by * 32 + ty + i * 8;
        tile[ty + i * 8][tx] = src[(size_t)r * C + c];
    }
    __syncthreads();
    int r2 = by * 32 + tx;
#pragma unroll
    for (int i = 0; i < 4; ++i) {
        int c2 = bx * 32 + ty + i * 8;
        dst[(size_t)c2 * R + r2] = tile[tx][ty + i * 8];
    }
}

// ---------------- whole-circuit persistent kernel: one block = 2 batch columns ----------------
// All LDS gathers are b32:
//   exp-domain tables (p0,p2) : bf16x2 packed in u32 (bf16 = f32 exponent range, enough mantissa)
//   log2-domain tables (enc,s1): h2 (f16 = 11-bit mantissa needed for log-domain precision)
// LDS pool = 49152 B (2 blocks/CU, 32 waves/CU):
//   p0  : [0,     32768)  u32[8192]  bf16x2 EXP2-domain (written P0, read S1)
//   enc : [32768, 40968)  h2 [2050]  log2-domain        (written E,  read P0)
//   s1  : [32768, 49152)  h2 [4096]  log2-domain        (overlays enc; written S1, read P2)
//   p2  : [0,     32768)  u32[8192]  bf16x2 EXP2-domain (overlays p0; written P2, read S3)
// All sums in f32. No max-subtraction: p0 in 2^[-80,0], realistic p2 >= 2^-110 > bf16 min-normal.
// fmaxf(.,1e-37f) floors never trigger legitimately (legit S1 sums >= 8e-25, S3 >= ~8e-34... >1e-37);
// they only stop a pathological 0/NaN from poisoning the output.
__global__ __launch_bounds__(1024, 8) void pipeline_kernel(const float* __restrict__ pos_t,  // [4096][1024]
                                                           const int4* __restrict__ idx0,    // [8192]
                                                           const int4* __restrict__ idx1,    // [4096][2]
                                                           const int4* __restrict__ idx2,    // [8192]
                                                           const int4* __restrict__ idx3,    // [2048][2]
                                                           float* __restrict__ out_t) {      // [4096][2048]
    __shared__ __align__(16) char pool[49152];
    unsigned* p0  = reinterpret_cast<unsigned*>(pool);
    h2*       enc = reinterpret_cast<h2*>(pool + 32768);
    h2*       s1  = reinterpret_cast<h2*>(pool + 32768);
    unsigned* p2  = reinterpret_cast<unsigned*>(pool);

    const int tid = threadIdx.x;
    const int c0 = blockIdx.x * 2;  // this block's two batch columns

    // ---- E: encode (log2 domain, h2 storage) ----
    {
        float a = pos_t[(size_t)c0 * NVARS + tid];
        float b = pos_t[(size_t)(c0 + 1) * NVARS + tid];
        h2 e0, e1;
        e0.x = (_Float16)(a * LOG2E);
        e0.y = (_Float16)(b * LOG2E);
        e1.x = (_Float16)(log1mexp_f(a) * LOG2E);
        e1.y = (_Float16)(log1mexp_f(b) * LOG2E);
        enc[2 + 2 * tid] = e0;
        enc[3 + 2 * tid] = e1;
        if (tid == 0) {
            h2 ni, z;
            ni.x = (_Float16)(-INFINITY); ni.y = (_Float16)(-INFINITY);
            z.x  = (_Float16)0.f;         z.y  = (_Float16)0.f;
            enc[0] = ni;  // row 0: never gathered (idx0 >= 1)
            enc[1] = z;   // row 1: log(1)
        }
    }
    __syncthreads();

    // ---- P0: gather-4 from enc (b32), f32 sum, store 2^p0 as bf16x2 (b32) ----
    for (int i = 0; i < ROWS_P0 / 1024; ++i) {
        int r = tid + i * 1024;
        int4 ix = idx0[r];
        h2 v0 = enc[ix.x], v1 = enc[ix.y], v2 = enc[ix.z], v3 = enc[ix.w];
        float ax = ((float)v0.x + (float)v1.x) + ((float)v2.x + (float)v3.x);
        float ay = ((float)v0.y + (float)v1.y) + ((float)v2.y + (float)v3.y);
        p0[r] = pk_bf16(fexp2(ax), fexp2(ay));
    }
    __syncthreads();

    // ---- S1: gather-8 from p0 (b32, exp2-domain bf16x2), f32 sum, log2, store h2 ----
    for (int i = 0; i < ROWS_S1 / 1024; ++i) {
        int r = tid + i * 1024;
        int4 a = idx1[2 * r], b = idx1[2 * r + 1];
        unsigned u0 = p0[a.x], u1 = p0[a.y], u2 = p0[a.z], u3 = p0[a.w];
        unsigned u4 = p0[b.x], u5 = p0[b.y], u6 = p0[b.z], u7 = p0[b.w];
        float sx = ((bf_lo(u0) + bf_lo(u1)) + (bf_lo(u2) + bf_lo(u3))) +
                   ((bf_lo(u4) + bf_lo(u5)) + (bf_lo(u6) + bf_lo(u7)));
        float sy = ((bf_hi(u0) + bf_hi(u1)) + (bf_hi(u2) + bf_hi(u3))) +
                   ((bf_hi(u4) + bf_hi(u5)) + (bf_hi(u6) + bf_hi(u7)));
        h2 o;
        o.x = (_Float16)flog2(fmaxf(sx, 1e-37f));
        o.y = (_Float16)flog2(fmaxf(sy, 1e-37f));
        s1[r] = o;
    }
    __syncthreads();

    // ---- P2: gather-4 from s1 (b32), f32 sum, store 2^p2 as bf16x2 (b32) ----
    for (int i = 0; i < ROWS_P2 / 1024; ++i) {
        int r = tid + i * 1024;
        int4 ix = idx2[r];
        h2 v0 = s1[ix.x], v1 = s1[ix.y], v2 = s1[ix.z], v3 = s1[ix.w];
        float ax = ((float)v0.x + (float)v1.x) + ((float)v2.x + (float)v3.x);
        float ay = ((float)v0.y + (float)v1.y) + ((float)v2.y + (float)v3.y);
        p2[r] = pk_bf16(fexp2(ax), fexp2(ay));
    }
    __syncthreads();

    // ---- S3: gather-8 from p2 (b32), f32 sum, log2 -> ln, coalesced column writes ----
    for (int i = 0; i < ROWS_S3 / 1024; ++i) {
        int r = tid + i * 1024;
        int4 a = idx3[2 * r], b = idx3[2 * r + 1];
        unsigned u0 = p2[a.x], u1 = p2[a.y], u2 = p2[a.z], u3 = p2[a.w];
        unsigned u4 = p2[b.x], u5 = p2[b.y], u6 = p2[b.z], u7 = p2[b.w];
        float sx = ((bf_lo(u0) + bf_lo(u1)) + (bf_lo(u2) + bf_lo(u3))) +
                   ((bf_lo(u4) + bf_lo(u5)) + (bf_lo(u6) + bf_lo(u7)));
        float sy = ((bf_hi(u0) + bf_hi(u1)) + (bf_hi(u2) + bf_hi(u3))) +
                   ((bf_hi(u4) + bf_hi(u5)) + (bf_hi(u6) + bf_hi(u7)));
        out_t[(size_t)c0 * ROWS_S3 + r] = flog2(fmaxf(sx, 1e-37f)) * LN2;
        out_t[(size_t)(c0 + 1) * ROWS_S3 + r] = flog2(fmaxf(sy, 1e-37f)) * LN2;
    }
}

extern "C" void kernel_launch(void* const* d_in, const int* in_sizes, int n_in,
                              void* d_out, int out_size, void* d_ws, size_t ws_size,
                              hipStream_t stream) {
    const float* pos  = (const float*)d_in[0];
    const int4*  idx0 = (const int4*)d_in[1];
    const int4*  idx1 = (const int4*)d_in[2];
    const int4*  idx2 = (const int4*)d_in[3];
    const int4*  idx3 = (const int4*)d_in[4];
    float*       out  = (float*)d_out;
    char*        ws   = (char*)d_ws;

    // ws layout: pos_t [4096][1024] (16 MB) | out_t [4096][2048] (32 MB)
    float* pos_t = (float*)ws;
    float* out_t = (float*)(ws + (size_t)BATCH * NVARS * sizeof(float));

    // 1) transpose pos [1024][4096] -> pos_t [4096][1024]
    transpose_kernel<<<dim3(BATCH / 32, NVARS / 32), dim3(32, 8), 0, stream>>>(pos, pos_t, NVARS, BATCH);

    // 2) whole circuit in LDS, one block per column pair (2 blocks/CU)
    pipeline_kernel<<<dim3(BATCH / 2), dim3(1024), 0, stream>>>(pos_t, idx0, idx1, idx2, idx3, out_t);

    // 3) transpose out_t [4096][2048] -> out [2048][4096]
    transpose_kernel<<<dim3(ROWS_S3 / 32, BATCH / 32), dim3(32, 8), 0, stream>>>(out_t, out, BATCH, ROWS_S3);
}

// Round 7
// 76.984 us; speedup vs baseline: 1.0819x; 1.0819x over previous
//
#include <hip/hip_runtime.h>
#include <math.h>

// Problem geometry (fixed by reference)
#define BATCH   4096
#define NVARS   1024
#define ROWS_P0 8192
#define ROWS_S1 4096
#define ROWS_P2 8192
#define ROWS_S3 2048

#define LOG2E 1.4426950408889634f
#define LN2   0.6931471805599453f

typedef _Float16 h4 __attribute__((ext_vector_type(4)));

__device__ __forceinline__ float log1mexp_f(float x) {
    // accurate log(1 - exp(x)) for x < 0 (Maechler 2012) — libm for precision near 0-
    if (x > -0.6931471805599453f) return logf(-expm1f(x));
    return log1pf(-expf(x));
}

__device__ __forceinline__ float fexp2(float x) { return __builtin_amdgcn_exp2f(x); }
__device__ __forceinline__ float flog2(float x) { return __builtin_amdgcn_logf(x); }

// Pack two positive f32 -> bf16x2 in one u32 via explicit RNE bit-twiddle (round-6 proven).
__device__ __forceinline__ unsigned pk_bf16(float x, float y) {
    unsigned xb = __float_as_uint(x);
    unsigned yb = __float_as_uint(y);
    xb += 0x7FFFu + ((xb >> 16) & 1u);   // RNE round into bf16
    yb += 0x7FFFu + ((yb >> 16) & 1u);
    return (xb >> 16) | (yb & 0xFFFF0000u);
}
__device__ __forceinline__ float bf_lo(unsigned v) { return __uint_as_float(v << 16); }
__device__ __forceinline__ float bf_hi(unsigned v) { return __uint_as_float(v & 0xFFFF0000u); }

// ---------------- generic 32x32 tiled transpose: dst[c][r] = src[r][c] ----------------
__global__ __launch_bounds__(256) void transpose_kernel(const float* __restrict__ src,
                                                        float* __restrict__ dst,
                                                        int R, int C) {
    __shared__ float tile[32][33];
    int bx = blockIdx.x, by = blockIdx.y;    // bx tiles C, by tiles R
    int tx = threadIdx.x, ty = threadIdx.y;  // block (32, 8)
    int c = bx * 32 + tx;
#pragma unroll
    for (int i = 0; i < 4; ++i) {
        int r = by * 32 + ty + i * 8;
        tile[ty + i * 8][tx] = src[(size_t)r * C + c];
    }
    __syncthreads();
    int r2 = by * 32 + tx;
#pragma unroll
    for (int i = 0; i < 4; ++i) {
        int c2 = bx * 32 + ty + i * 8;
        dst[(size_t)c2 * R + r2] = tile[tx][ty + i * 8];
    }
}

// ---------------- whole-circuit persistent kernel: one block = 4 batch columns ----------------
// Round-6 lesson: LDS is issue-bound, not byte-bound -> b64 gathers serving 4 columns halve
// per-chip LDS instructions. Register-deferred table writes keep only ONE table live at a
// time -> LDS peak 64 KiB -> still 2 blocks/CU (32 waves).
//   enc : h4[2050]    log2-domain f16x4   live E  .. P0 reads
//   p0  : uint2[8192] EXP2-domain bf16x4  live P0b.. S1 reads   (overwrites enc)
//   s1  : h4[4096]    log2-domain f16x4   live S1b.. P2 reads   (overwrites p0)
//   p2  : uint2[8192] EXP2-domain bf16x4  live P2b.. S3 reads   (overwrites s1)
// All sums f32. No max-subtraction: p0 in 2^[-80,0], realistic p2 >= 2^-110 > bf16 min-normal.
// fmaxf(.,1e-37f) floors never trigger legitimately; they only stop pathological 0 -> -inf/NaN.
__global__ __launch_bounds__(1024, 8) void pipeline_kernel(const float* __restrict__ pos_t,  // [4096][1024]
                                                           const int4* __restrict__ idx0,    // [8192]
                                                           const int4* __restrict__ idx1,    // [4096][2]
                                                           const int4* __restrict__ idx2,    // [8192]
                                                           const int4* __restrict__ idx3,    // [2048][2]
                                                           float* __restrict__ out_t) {      // [4096][2048]
    __shared__ __align__(16) char pool[65536];
    h4*    enc = reinterpret_cast<h4*>(pool);      // [2050]  (16400 B)
    uint2* p0  = reinterpret_cast<uint2*>(pool);   // [8192]  (65536 B)
    h4*    s1  = reinterpret_cast<h4*>(pool);      // [4096]  (32768 B)
    uint2* p2  = reinterpret_cast<uint2*>(pool);   // [8192]  (65536 B)

    const int tid = threadIdx.x;
    const int c0 = blockIdx.x * 4;  // this block's four batch columns

    // ---- E: encode (log2 domain, f16x4 storage) ----
    {
        float a0 = pos_t[(size_t)(c0 + 0) * NVARS + tid];
        float a1 = pos_t[(size_t)(c0 + 1) * NVARS + tid];
        float a2 = pos_t[(size_t)(c0 + 2) * NVARS + tid];
        float a3 = pos_t[(size_t)(c0 + 3) * NVARS + tid];
        h4 ep, en;
        ep.x = (_Float16)(a0 * LOG2E); ep.y = (_Float16)(a1 * LOG2E);
        ep.z = (_Float16)(a2 * LOG2E); ep.w = (_Float16)(a3 * LOG2E);
        en.x = (_Float16)(log1mexp_f(a0) * LOG2E); en.y = (_Float16)(log1mexp_f(a1) * LOG2E);
        en.z = (_Float16)(log1mexp_f(a2) * LOG2E); en.w = (_Float16)(log1mexp_f(a3) * LOG2E);
        enc[2 + 2 * tid] = ep;
        enc[3 + 2 * tid] = en;
        if (tid == 0) {
            h4 ni, z;
            ni.x = ni.y = ni.z = ni.w = (_Float16)(-INFINITY);  // row 0: never gathered (idx0>=1)
            z.x = z.y = z.z = z.w = (_Float16)0.f;              // row 1: log(1)
            enc[0] = ni;
            enc[1] = z;
        }
    }
    __syncthreads();

    // ---- P0: gather-4 from enc (b64), f32 sums, 2^x, hold bf16x4 in regs ----
    uint2 hold0[8];
#pragma unroll
    for (int i = 0; i < ROWS_P0 / 1024; ++i) {
        int r = tid + i * 1024;
        int4 ix = idx0[r];
        h4 v0 = enc[ix.x], v1 = enc[ix.y], v2 = enc[ix.z], v3 = enc[ix.w];
        float sa = ((float)v0.x + (float)v1.x) + ((float)v2.x + (float)v3.x);
        float sb = ((float)v0.y + (float)v1.y) + ((float)v2.y + (float)v3.y);
        float sc = ((float)v0.z + (float)v1.z) + ((float)v2.z + (float)v3.z);
        float sd = ((float)v0.w + (float)v1.w) + ((float)v2.w + (float)v3.w);
        hold0[i] = make_uint2(pk_bf16(fexp2(sa), fexp2(sb)), pk_bf16(fexp2(sc), fexp2(sd)));
    }
    __syncthreads();  // all P0 reads of enc done
#pragma unroll
    for (int i = 0; i < ROWS_P0 / 1024; ++i) p0[tid + i * 1024] = hold0[i];
    __syncthreads();

    // ---- S1: gather-8 from p0 (b64, exp2-domain), f32 sums, log2, hold f16x4 in regs ----
    h4 hold1[4];
#pragma unroll
    for (int i = 0; i < ROWS_S1 / 1024; ++i) {
        int r = tid + i * 1024;
        int4 a = idx1[2 * r], b = idx1[2 * r + 1];
        uint2 u0 = p0[a.x], u1 = p0[a.y], u2 = p0[a.z], u3 = p0[a.w];
        uint2 u4 = p0[b.x], u5 = p0[b.y], u6 = p0[b.z], u7 = p0[b.w];
        float sa = ((bf_lo(u0.x) + bf_lo(u1.x)) + (bf_lo(u2.x) + bf_lo(u3.x))) +
                   ((bf_lo(u4.x) + bf_lo(u5.x)) + (bf_lo(u6.x) + bf_lo(u7.x)));
        float sb = ((bf_hi(u0.x) + bf_hi(u1.x)) + (bf_hi(u2.x) + bf_hi(u3.x))) +
                   ((bf_hi(u4.x) + bf_hi(u5.x)) + (bf_hi(u6.x) + bf_hi(u7.x)));
        float sc = ((bf_lo(u0.y) + bf_lo(u1.y)) + (bf_lo(u2.y) + bf_lo(u3.y))) +
                   ((bf_lo(u4.y) + bf_lo(u5.y)) + (bf_lo(u6.y) + bf_lo(u7.y)));
        float sd = ((bf_hi(u0.y) + bf_hi(u1.y)) + (bf_hi(u2.y) + bf_hi(u3.y))) +
                   ((bf_hi(u4.y) + bf_hi(u5.y)) + (bf_hi(u6.y) + bf_hi(u7.y)));
        h4 o;
        o.x = (_Float16)flog2(fmaxf(sa, 1e-37f));
        o.y = (_Float16)flog2(fmaxf(sb, 1e-37f));
        o.z = (_Float16)flog2(fmaxf(sc, 1e-37f));
        o.w = (_Float16)flog2(fmaxf(sd, 1e-37f));
        hold1[i] = o;
    }
    __syncthreads();  // all S1 reads of p0 done
#pragma unroll
    for (int i = 0; i < ROWS_S1 / 1024; ++i) s1[tid + i * 1024] = hold1[i];
    __syncthreads();

    // ---- P2: gather-4 from s1 (b64), f32 sums, 2^x, hold bf16x4 in regs ----
    uint2 hold2[8];
#pragma unroll
    for (int i = 0; i < ROWS_P2 / 1024; ++i) {
        int r = tid + i * 1024;
        int4 ix = idx2[r];
        h4 v0 = s1[ix.x], v1 = s1[ix.y], v2 = s1[ix.z], v3 = s1[ix.w];
        float sa = ((float)v0.x + (float)v1.x) + ((float)v2.x + (float)v3.x);
        float sb = ((float)v0.y + (float)v1.y) + ((float)v2.y + (float)v3.y);
        float sc = ((float)v0.z + (float)v1.z) + ((float)v2.z + (float)v3.z);
        float sd = ((float)v0.w + (float)v1.w) + ((float)v2.w + (float)v3.w);
        hold2[i] = make_uint2(pk_bf16(fexp2(sa), fexp2(sb)), pk_bf16(fexp2(sc), fexp2(sd)));
    }
    __syncthreads();  // all P2 reads of s1 done
#pragma unroll
    for (int i = 0; i < ROWS_P2 / 1024; ++i) p2[tid + i * 1024] = hold2[i];
    __syncthreads();

    // ---- S3: gather-8 from p2 (b64), f32 sums, log2 -> ln, coalesced column writes ----
#pragma unroll
    for (int i = 0; i < ROWS_S3 / 1024; ++i) {
        int r = tid + i * 1024;
        int4 a = idx3[2 * r], b = idx3[2 * r + 1];
        uint2 u0 = p2[a.x], u1 = p2[a.y], u2 = p2[a.z], u3 = p2[a.w];
        uint2 u4 = p2[b.x], u5 = p2[b.y], u6 = p2[b.z], u7 = p2[b.w];
        float sa = ((bf_lo(u0.x) + bf_lo(u1.x)) + (bf_lo(u2.x) + bf_lo(u3.x))) +
                   ((bf_lo(u4.x) + bf_lo(u5.x)) + (bf_lo(u6.x) + bf_lo(u7.x)));
        float sb = ((bf_hi(u0.x) + bf_hi(u1.x)) + (bf_hi(u2.x) + bf_hi(u3.x))) +
                   ((bf_hi(u4.x) + bf_hi(u5.x)) + (bf_hi(u6.x) + bf_hi(u7.x)));
        float sc = ((bf_lo(u0.y) + bf_lo(u1.y)) + (bf_lo(u2.y) + bf_lo(u3.y))) +
                   ((bf_lo(u4.y) + bf_lo(u5.y)) + (bf_lo(u6.y) + bf_lo(u7.y)));
        float sd = ((bf_hi(u0.y) + bf_hi(u1.y)) + (bf_hi(u2.y) + bf_hi(u3.y))) +
                   ((bf_hi(u4.y) + bf_hi(u5.y)) + (bf_hi(u6.y) + bf_hi(u7.y)));
        out_t[(size_t)(c0 + 0) * ROWS_S3 + r] = flog2(fmaxf(sa, 1e-37f)) * LN2;
        out_t[(size_t)(c0 + 1) * ROWS_S3 + r] = flog2(fmaxf(sb, 1e-37f)) * LN2;
        out_t[(size_t)(c0 + 2) * ROWS_S3 + r] = flog2(fmaxf(sc, 1e-37f)) * LN2;
        out_t[(size_t)(c0 + 3) * ROWS_S3 + r] = flog2(fmaxf(sd, 1e-37f)) * LN2;
    }
}

extern "C" void kernel_launch(void* const* d_in, const int* in_sizes, int n_in,
                              void* d_out, int out_size, void* d_ws, size_t ws_size,
                              hipStream_t stream) {
    const float* pos  = (const float*)d_in[0];
    const int4*  idx0 = (const int4*)d_in[1];
    const int4*  idx1 = (const int4*)d_in[2];
    const int4*  idx2 = (const int4*)d_in[3];
    const int4*  idx3 = (const int4*)d_in[4];
    float*       out  = (float*)d_out;
    char*        ws   = (char*)d_ws;

    // ws layout: pos_t [4096][1024] (16 MB) | out_t [4096][2048] (32 MB)
    float* pos_t = (float*)ws;
    float* out_t = (float*)(ws + (size_t)BATCH * NVARS * sizeof(float));

    // 1) transpose pos [1024][4096] -> pos_t [4096][1024]
    transpose_kernel<<<dim3(BATCH / 32, NVARS / 32), dim3(32, 8), 0, stream>>>(pos, pos_t, NVARS, BATCH);

    // 2) whole circuit in LDS, one block per 4 columns (2 blocks/CU)
    pipeline_kernel<<<dim3(BATCH / 4), dim3(1024), 0, stream>>>(pos_t, idx0, idx1, idx2, idx3, out_t);

    // 3) transpose out_t [4096][2048] -> out [2048][4096]
    transpose_kernel<<<dim3(ROWS_S3 / 32, BATCH / 32), dim3(32, 8), 0, stream>>>(out_t, out, BATCH, ROWS_S3);
}

// Round 8
// 72.630 us; speedup vs baseline: 1.1468x; 1.0599x over previous
//
#include <hip/hip_runtime.h>
#include <math.h>

// Problem geometry (fixed by reference)
#define BATCH   4096
#define NVARS   1024
#define ROWS_P0 8192
#define ROWS_S1 4096
#define ROWS_P2 8192
#define ROWS_S3 2048

#define LOG2E 1.4426950408889634f
#define LN2   0.6931471805599453f

typedef _Float16 h4 __attribute__((ext_vector_type(4)));
typedef float    f2 __attribute__((ext_vector_type(2)));

__device__ __forceinline__ float log1mexp_f(float x) {
    // accurate log(1 - exp(x)) for x < 0 (Maechler 2012) — libm for precision near 0-
    if (x > -0.6931471805599453f) return logf(-expm1f(x));
    return log1pf(-expf(x));
}

__device__ __forceinline__ float fexp2(float x) { return __builtin_amdgcn_exp2f(x); }
__device__ __forceinline__ float flog2(float x) { return __builtin_amdgcn_logf(x); }

// Pack two positive f32 (<=1.0) -> bf16x2 in one u32, round-half-up (5 VALU ops).
// No overflow possible: inputs are probabilities <= 1.0.
__device__ __forceinline__ unsigned pk_bf16(float x, float y) {
    unsigned xb = __float_as_uint(x) + 0x8000u;
    unsigned yb = __float_as_uint(y) + 0x8000u;
    return (xb >> 16) | (yb & 0xFFFF0000u);
}
__device__ __forceinline__ float bf_lo(unsigned v) { return __uint_as_float(v << 16); }
__device__ __forceinline__ float bf_hi(unsigned v) { return __uint_as_float(v & 0xFFFF0000u); }
__device__ __forceinline__ f2 mk2(float a, float b) { f2 r; r.x = a; r.y = b; return r; }

// ---------------- 32x32 tiled transpose: dst[c][r] = src[r][c] ----------------
__global__ __launch_bounds__(256) void transpose_kernel(const float* __restrict__ src,
                                                        float* __restrict__ dst,
                                                        int R, int C) {
    __shared__ float tile[32][33];
    int bx = blockIdx.x, by = blockIdx.y;
    int tx = threadIdx.x, ty = threadIdx.y;  // block (32, 8)
    int c = bx * 32 + tx;
#pragma unroll
    for (int i = 0; i < 4; ++i) {
        int r = by * 32 + ty + i * 8;
        tile[ty + i * 8][tx] = src[(size_t)r * C + c];
    }
    __syncthreads();
    int r2 = by * 32 + tx;
#pragma unroll
    for (int i = 0; i < 4; ++i) {
        int c2 = bx * 32 + ty + i * 8;
        dst[(size_t)c2 * R + r2] = tile[tx][ty + i * 8];
    }
}

// ---------------- whole-circuit persistent kernel: one block = 4 batch columns ----------------
// Round-7 lesson: VALU-bound (78% busy, LDS well under wall). This round: packed math.
//   P-layers: v_pk_add_f16 2-level tree on gathered h4 (6 pk + 4 cvt vs 16 cvt + 12 add)
//   S-layers: v_pk_add_f32 trees on unpacked bf16 pairs (14 pk vs 28 scalar adds)
//   bf16 pack: round-half-up, 5 ops. S3 stores float4 directly to out (no out_t round-trip).
// Register-deferred table writes keep ONE table live -> LDS 64 KiB -> 2 blocks/CU (32 waves).
//   enc : h4[2050]    log2-domain f16x4   | p0/p2 : uint2[8192] EXP2-domain bf16x4
//   s1  : h4[4096]    log2-domain f16x4   (tables overlay one another phase by phase)
// All reduction trees through f32 except the P-layer 4-sums (f16, error <= 2 ulp at the
// magnitudes that dominate the LSE). No max-subtraction: p0 in 2^[-80,0], realistic
// p2 >= 2^-110 > bf16 min-normal. fmax floors never trigger legitimately.
__global__ __launch_bounds__(1024, 8) void pipeline_kernel(const float* __restrict__ pos_t,  // [4096][1024]
                                                           const int4* __restrict__ idx0,    // [8192]
                                                           const int4* __restrict__ idx1,    // [4096][2]
                                                           const int4* __restrict__ idx2,    // [8192]
                                                           const int4* __restrict__ idx3,    // [2048][2]
                                                           float* __restrict__ out) {        // [2048][4096]
    __shared__ __align__(16) char pool[65536];
    h4*    enc = reinterpret_cast<h4*>(pool);      // [2050]  (16400 B)
    uint2* p0  = reinterpret_cast<uint2*>(pool);   // [8192]  (65536 B)
    h4*    s1  = reinterpret_cast<h4*>(pool);      // [4096]  (32768 B)
    uint2* p2  = reinterpret_cast<uint2*>(pool);   // [8192]  (65536 B)

    const int tid = threadIdx.x;
    const int c0 = blockIdx.x * 4;  // this block's four batch columns

    // ---- E: encode (log2 domain, f16x4 storage) ----
    {
        float a0 = pos_t[(size_t)(c0 + 0) * NVARS + tid];
        float a1 = pos_t[(size_t)(c0 + 1) * NVARS + tid];
        float a2 = pos_t[(size_t)(c0 + 2) * NVARS + tid];
        float a3 = pos_t[(size_t)(c0 + 3) * NVARS + tid];
        h4 ep, en;
        ep.x = (_Float16)(a0 * LOG2E); ep.y = (_Float16)(a1 * LOG2E);
        ep.z = (_Float16)(a2 * LOG2E); ep.w = (_Float16)(a3 * LOG2E);
        en.x = (_Float16)(log1mexp_f(a0) * LOG2E); en.y = (_Float16)(log1mexp_f(a1) * LOG2E);
        en.z = (_Float16)(log1mexp_f(a2) * LOG2E); en.w = (_Float16)(log1mexp_f(a3) * LOG2E);
        enc[2 + 2 * tid] = ep;
        enc[3 + 2 * tid] = en;
        if (tid == 0) {
            h4 ni, z;
            ni.x = ni.y = ni.z = ni.w = (_Float16)(-INFINITY);  // row 0: never gathered (idx0>=1)
            z.x = z.y = z.z = z.w = (_Float16)0.f;              // row 1: log(1)
            enc[0] = ni;
            enc[1] = z;
        }
    }
    __syncthreads();

    // ---- P0: gather-4 from enc (b64), packed-f16 sum tree, 2^x, hold bf16x4 in regs ----
    uint2 hold0[8];
#pragma unroll
    for (int i = 0; i < ROWS_P0 / 1024; ++i) {
        int r = tid + i * 1024;
        int4 ix = idx0[r];
        h4 v0 = enc[ix.x], v1 = enc[ix.y], v2 = enc[ix.z], v3 = enc[ix.w];
        h4 s = (v0 + v1) + (v2 + v3);                 // v_pk_add_f16 x6
        hold0[i] = make_uint2(pk_bf16(fexp2((float)s.x), fexp2((float)s.y)),
                              pk_bf16(fexp2((float)s.z), fexp2((float)s.w)));
    }
    __syncthreads();  // all P0 reads of enc done
#pragma unroll
    for (int i = 0; i < ROWS_P0 / 1024; ++i) p0[tid + i * 1024] = hold0[i];
    __syncthreads();

    // ---- S1: gather-8 from p0 (b64, exp2-domain), packed-f32 sum trees, log2, hold f16x4 ----
    h4 hold1[4];
#pragma unroll
    for (int i = 0; i < ROWS_S1 / 1024; ++i) {
        int r = tid + i * 1024;
        int4 a = idx1[2 * r], b = idx1[2 * r + 1];
        uint2 u0 = p0[a.x], u1 = p0[a.y], u2 = p0[a.z], u3 = p0[a.w];
        uint2 u4 = p0[b.x], u5 = p0[b.y], u6 = p0[b.z], u7 = p0[b.w];
        f2 ab = (mk2(bf_lo(u0.x), bf_hi(u0.x)) + mk2(bf_lo(u1.x), bf_hi(u1.x))) +
                (mk2(bf_lo(u2.x), bf_hi(u2.x)) + mk2(bf_lo(u3.x), bf_hi(u3.x)));
        ab = ab + ((mk2(bf_lo(u4.x), bf_hi(u4.x)) + mk2(bf_lo(u5.x), bf_hi(u5.x))) +
                   (mk2(bf_lo(u6.x), bf_hi(u6.x)) + mk2(bf_lo(u7.x), bf_hi(u7.x))));
        f2 cd = (mk2(bf_lo(u0.y), bf_hi(u0.y)) + mk2(bf_lo(u1.y), bf_hi(u1.y))) +
                (mk2(bf_lo(u2.y), bf_hi(u2.y)) + mk2(bf_lo(u3.y), bf_hi(u3.y)));
        cd = cd + ((mk2(bf_lo(u4.y), bf_hi(u4.y)) + mk2(bf_lo(u5.y), bf_hi(u5.y))) +
                   (mk2(bf_lo(u6.y), bf_hi(u6.y)) + mk2(bf_lo(u7.y), bf_hi(u7.y))));
        ab = __builtin_elementwise_max(ab, mk2(1e-37f, 1e-37f));
        cd = __builtin_elementwise_max(cd, mk2(1e-37f, 1e-37f));
        h4 o;
        o.x = (_Float16)flog2(ab.x);
        o.y = (_Float16)flog2(ab.y);
        o.z = (_Float16)flog2(cd.x);
        o.w = (_Float16)flog2(cd.y);
        hold1[i] = o;
    }
    __syncthreads();  // all S1 reads of p0 done
#pragma unroll
    for (int i = 0; i < ROWS_S1 / 1024; ++i) s1[tid + i * 1024] = hold1[i];
    __syncthreads();

    // ---- P2: gather-4 from s1 (b64), packed-f16 sum tree, 2^x, hold bf16x4 in regs ----
    uint2 hold2[8];
#pragma unroll
    for (int i = 0; i < ROWS_P2 / 1024; ++i) {
        int r = tid + i * 1024;
        int4 ix = idx2[r];
        h4 v0 = s1[ix.x], v1 = s1[ix.y], v2 = s1[ix.z], v3 = s1[ix.w];
        h4 s = (v0 + v1) + (v2 + v3);                 // v_pk_add_f16 x6
        hold2[i] = make_uint2(pk_bf16(fexp2((float)s.x), fexp2((float)s.y)),
                              pk_bf16(fexp2((float)s.z), fexp2((float)s.w)));
    }
    __syncthreads();  // all P2 reads of s1 done
#pragma unroll
    for (int i = 0; i < ROWS_P2 / 1024; ++i) p2[tid + i * 1024] = hold2[i];
    __syncthreads();

    // ---- S3: gather-8 from p2 (b64), packed-f32 trees, log2 -> ln, direct float4 out ----
#pragma unroll
    for (int i = 0; i < ROWS_S3 / 1024; ++i) {
        int r = tid + i * 1024;
        int4 a = idx3[2 * r], b = idx3[2 * r + 1];
        uint2 u0 = p2[a.x], u1 = p2[a.y], u2 = p2[a.z], u3 = p2[a.w];
        uint2 u4 = p2[b.x], u5 = p2[b.y], u6 = p2[b.z], u7 = p2[b.w];
        f2 ab = (mk2(bf_lo(u0.x), bf_hi(u0.x)) + mk2(bf_lo(u1.x), bf_hi(u1.x))) +
                (mk2(bf_lo(u2.x), bf_hi(u2.x)) + mk2(bf_lo(u3.x), bf_hi(u3.x)));
        ab = ab + ((mk2(bf_lo(u4.x), bf_hi(u4.x)) + mk2(bf_lo(u5.x), bf_hi(u5.x))) +
                   (mk2(bf_lo(u6.x), bf_hi(u6.x)) + mk2(bf_lo(u7.x), bf_hi(u7.x))));
        f2 cd = (mk2(bf_lo(u0.y), bf_hi(u0.y)) + mk2(bf_lo(u1.y), bf_hi(u1.y))) +
                (mk2(bf_lo(u2.y), bf_hi(u2.y)) + mk2(bf_lo(u3.y), bf_hi(u3.y)));
        cd = cd + ((mk2(bf_lo(u4.y), bf_hi(u4.y)) + mk2(bf_lo(u5.y), bf_hi(u5.y))) +
                   (mk2(bf_lo(u6.y), bf_hi(u6.y)) + mk2(bf_lo(u7.y), bf_hi(u7.y))));
        ab = __builtin_elementwise_max(ab, mk2(1e-37f, 1e-37f));
        cd = __builtin_elementwise_max(cd, mk2(1e-37f, 1e-37f));
        float4 o4;
        o4.x = flog2(ab.x) * LN2;
        o4.y = flog2(ab.y) * LN2;
        o4.z = flog2(cd.x) * LN2;
        o4.w = flog2(cd.y) * LN2;
        // direct transposed store: 16B per lane, full lines assembled in L2
        reinterpret_cast<float4*>(out)[(size_t)r * (BATCH / 4) + (c0 >> 2)] = o4;
    }
}

extern "C" void kernel_launch(void* const* d_in, const int* in_sizes, int n_in,
                              void* d_out, int out_size, void* d_ws, size_t ws_size,
                              hipStream_t stream) {
    const float* pos  = (const float*)d_in[0];
    const int4*  idx0 = (const int4*)d_in[1];
    const int4*  idx1 = (const int4*)d_in[2];
    const int4*  idx2 = (const int4*)d_in[3];
    const int4*  idx3 = (const int4*)d_in[4];
    float*       out  = (float*)d_out;
    char*        ws   = (char*)d_ws;

    // ws layout: pos_t [4096][1024] (16 MB)
    float* pos_t = (float*)ws;

    // 1) transpose pos [1024][4096] -> pos_t [4096][1024]
    transpose_kernel<<<dim3(BATCH / 32, NVARS / 32), dim3(32, 8), 0, stream>>>(pos, pos_t, NVARS, BATCH);

    // 2) whole circuit in LDS, one block per 4 columns (2 blocks/CU); writes out directly
    pipeline_kernel<<<dim3(BATCH / 4), dim3(1024), 0, stream>>>(pos_t, idx0, idx1, idx2, idx3, out);
}

// Round 9
// 61.528 us; speedup vs baseline: 1.3537x; 1.1804x over previous
//
#include <hip/hip_runtime.h>
#include <math.h>

// Problem geometry (fixed by reference)
#define BATCH   4096
#define NVARS   1024
#define ROWS_P0 8192
#define ROWS_S1 4096
#define ROWS_P2 8192
#define ROWS_S3 2048

#define LOG2E 1.4426950408889634f
#define LN2   0.6931471805599453f

typedef _Float16 h4 __attribute__((ext_vector_type(4)));
typedef float    f2 __attribute__((ext_vector_type(2)));

__device__ __forceinline__ float log1mexp_f(float x) {
    // accurate log(1 - exp(x)) for x < 0 (Maechler 2012) — libm for precision near 0-
    if (x > -0.6931471805599453f) return logf(-expm1f(x));
    return log1pf(-expf(x));
}

__device__ __forceinline__ float fexp2(float x) { return __builtin_amdgcn_exp2f(x); }
__device__ __forceinline__ float flog2(float x) { return __builtin_amdgcn_logf(x); }

// Pack two positive f32 (<=1.0) -> bf16x2 in one u32, round-half-up (5 VALU ops).
__device__ __forceinline__ unsigned pk_bf16(float x, float y) {
    unsigned xb = __float_as_uint(x) + 0x8000u;
    unsigned yb = __float_as_uint(y) + 0x8000u;
    return (xb >> 16) | (yb & 0xFFFF0000u);
}
__device__ __forceinline__ float bf_lo(unsigned v) { return __uint_as_float(v << 16); }
__device__ __forceinline__ float bf_hi(unsigned v) { return __uint_as_float(v & 0xFFFF0000u); }
__device__ __forceinline__ f2 mk2(float a, float b) { f2 r; r.x = a; r.y = b; return r; }

// ---------------- 32x32 tiled transpose: dst[c][r] = src[r][c] ----------------
__global__ __launch_bounds__(256) void transpose_kernel(const float* __restrict__ src,
                                                        float* __restrict__ dst,
                                                        int R, int C) {
    __shared__ float tile[32][33];
    int bx = blockIdx.x, by = blockIdx.y;
    int tx = threadIdx.x, ty = threadIdx.y;  // block (32, 8)
    int c = bx * 32 + tx;
#pragma unroll
    for (int i = 0; i < 4; ++i) {
        int r = by * 32 + ty + i * 8;
        tile[ty + i * 8][tx] = src[(size_t)r * C + c];
    }
    __syncthreads();
    int r2 = by * 32 + tx;
#pragma unroll
    for (int i = 0; i < 4; ++i) {
        int c2 = bx * 32 + ty + i * 8;
        dst[(size_t)c2 * R + r2] = tile[tx][ty + i * 8];
    }
}

// ---------------- whole-circuit persistent kernel: one block = 4 batch columns ----------------
// Round-8 lesson: direct scattered float4 stores write-amplified 2x because the 8 blocks
// sharing a 128B output line landed on 8 different XCDs (per-XCD L2s can't combine).
// Fix: bijective XCD-chunked swizzle (T1) — XCD k owns contiguous columns [512k, 512k+512),
// so line-sharing blocks co-reside on one XCD L2 and writes combine before eviction.
// Structure otherwise as round 8: packed math, register-deferred tables (one live at a
// time, 64 KiB -> 2 blocks/CU, 32 waves), all-b64 LDS gathers serving 4 columns.
//   enc : h4[2050]    log2-domain f16x4   | p0/p2 : uint2[8192] EXP2-domain bf16x4
//   s1  : h4[4096]    log2-domain f16x4   (tables overlay one another phase by phase)
// No max-subtraction: p0 in 2^[-80,0], realistic p2 >= 2^-110 > bf16 min-normal.
// fmax floors never trigger legitimately; they only stop pathological 0 -> -inf/NaN.
__global__ __launch_bounds__(1024, 8) void pipeline_kernel(const float* __restrict__ pos_t,  // [4096][1024]
                                                           const int4* __restrict__ idx0,    // [8192]
                                                           const int4* __restrict__ idx1,    // [4096][2]
                                                           const int4* __restrict__ idx2,    // [8192]
                                                           const int4* __restrict__ idx3,    // [2048][2]
                                                           float* __restrict__ out) {        // [2048][4096]
    __shared__ __align__(16) char pool[65536];
    h4*    enc = reinterpret_cast<h4*>(pool);      // [2050]  (16400 B)
    uint2* p0  = reinterpret_cast<uint2*>(pool);   // [8192]  (65536 B)
    h4*    s1  = reinterpret_cast<h4*>(pool);      // [4096]  (32768 B)
    uint2* p2  = reinterpret_cast<uint2*>(pool);   // [8192]  (65536 B)

    const int tid = threadIdx.x;
    // XCD-chunked bijective swizzle: 1024 blocks, 8 XCDs, 128 blocks/XCD chunk.
    // XCD k (bid%8==k under round-robin dispatch) gets original chunk [128k,128k+128).
    const int bid = blockIdx.x;
    const int swz = ((bid & 7) << 7) | (bid >> 3);
    const int c0 = swz * 4;  // this block's four batch columns

    // ---- E: encode (log2 domain, f16x4 storage) ----
    {
        float a0 = pos_t[(size_t)(c0 + 0) * NVARS + tid];
        float a1 = pos_t[(size_t)(c0 + 1) * NVARS + tid];
        float a2 = pos_t[(size_t)(c0 + 2) * NVARS + tid];
        float a3 = pos_t[(size_t)(c0 + 3) * NVARS + tid];
        h4 ep, en;
        ep.x = (_Float16)(a0 * LOG2E); ep.y = (_Float16)(a1 * LOG2E);
        ep.z = (_Float16)(a2 * LOG2E); ep.w = (_Float16)(a3 * LOG2E);
        en.x = (_Float16)(log1mexp_f(a0) * LOG2E); en.y = (_Float16)(log1mexp_f(a1) * LOG2E);
        en.z = (_Float16)(log1mexp_f(a2) * LOG2E); en.w = (_Float16)(log1mexp_f(a3) * LOG2E);
        enc[2 + 2 * tid] = ep;
        enc[3 + 2 * tid] = en;
        if (tid == 0) {
            h4 ni, z;
            ni.x = ni.y = ni.z = ni.w = (_Float16)(-INFINITY);  // row 0: never gathered (idx0>=1)
            z.x = z.y = z.z = z.w = (_Float16)0.f;              // row 1: log(1)
            enc[0] = ni;
            enc[1] = z;
        }
    }
    __syncthreads();

    // ---- P0: gather-4 from enc (b64), packed-f16 sum tree, 2^x, hold bf16x4 in regs ----
    uint2 hold0[8];
#pragma unroll
    for (int i = 0; i < ROWS_P0 / 1024; ++i) {
        int r = tid + i * 1024;
        int4 ix = idx0[r];
        h4 v0 = enc[ix.x], v1 = enc[ix.y], v2 = enc[ix.z], v3 = enc[ix.w];
        h4 s = (v0 + v1) + (v2 + v3);                 // v_pk_add_f16 x6
        hold0[i] = make_uint2(pk_bf16(fexp2((float)s.x), fexp2((float)s.y)),
                              pk_bf16(fexp2((float)s.z), fexp2((float)s.w)));
    }
    __syncthreads();  // all P0 reads of enc done
#pragma unroll
    for (int i = 0; i < ROWS_P0 / 1024; ++i) p0[tid + i * 1024] = hold0[i];
    __syncthreads();

    // ---- S1: gather-8 from p0 (b64, exp2-domain), packed-f32 sum trees, log2, hold f16x4 ----
    h4 hold1[4];
#pragma unroll
    for (int i = 0; i < ROWS_S1 / 1024; ++i) {
        int r = tid + i * 1024;
        int4 a = idx1[2 * r], b = idx1[2 * r + 1];
        uint2 u0 = p0[a.x], u1 = p0[a.y], u2 = p0[a.z], u3 = p0[a.w];
        uint2 u4 = p0[b.x], u5 = p0[b.y], u6 = p0[b.z], u7 = p0[b.w];
        f2 ab = (mk2(bf_lo(u0.x), bf_hi(u0.x)) + mk2(bf_lo(u1.x), bf_hi(u1.x))) +
                (mk2(bf_lo(u2.x), bf_hi(u2.x)) + mk2(bf_lo(u3.x), bf_hi(u3.x)));
        ab = ab + ((mk2(bf_lo(u4.x), bf_hi(u4.x)) + mk2(bf_lo(u5.x), bf_hi(u5.x))) +
                   (mk2(bf_lo(u6.x), bf_hi(u6.x)) + mk2(bf_lo(u7.x), bf_hi(u7.x))));
        f2 cd = (mk2(bf_lo(u0.y), bf_hi(u0.y)) + mk2(bf_lo(u1.y), bf_hi(u1.y))) +
                (mk2(bf_lo(u2.y), bf_hi(u2.y)) + mk2(bf_lo(u3.y), bf_hi(u3.y)));
        cd = cd + ((mk2(bf_lo(u4.y), bf_hi(u4.y)) + mk2(bf_lo(u5.y), bf_hi(u5.y))) +
                   (mk2(bf_lo(u6.y), bf_hi(u6.y)) + mk2(bf_lo(u7.y), bf_hi(u7.y))));
        ab = __builtin_elementwise_max(ab, mk2(1e-37f, 1e-37f));
        cd = __builtin_elementwise_max(cd, mk2(1e-37f, 1e-37f));
        h4 o;
        o.x = (_Float16)flog2(ab.x);
        o.y = (_Float16)flog2(ab.y);
        o.z = (_Float16)flog2(cd.x);
        o.w = (_Float16)flog2(cd.y);
        hold1[i] = o;
    }
    __syncthreads();  // all S1 reads of p0 done
#pragma unroll
    for (int i = 0; i < ROWS_S1 / 1024; ++i) s1[tid + i * 1024] = hold1[i];
    __syncthreads();

    // ---- P2: gather-4 from s1 (b64), packed-f16 sum tree, 2^x, hold bf16x4 in regs ----
    uint2 hold2[8];
#pragma unroll
    for (int i = 0; i < ROWS_P2 / 1024; ++i) {
        int r = tid + i * 1024;
        int4 ix = idx2[r];
        h4 v0 = s1[ix.x], v1 = s1[ix.y], v2 = s1[ix.z], v3 = s1[ix.w];
        h4 s = (v0 + v1) + (v2 + v3);                 // v_pk_add_f16 x6
        hold2[i] = make_uint2(pk_bf16(fexp2((float)s.x), fexp2((float)s.y)),
                              pk_bf16(fexp2((float)s.z), fexp2((float)s.w)));
    }
    __syncthreads();  // all P2 reads of s1 done
#pragma unroll
    for (int i = 0; i < ROWS_P2 / 1024; ++i) p2[tid + i * 1024] = hold2[i];
    __syncthreads();

    // ---- S3: gather-8 from p2 (b64), packed-f32 trees, log2 -> ln, direct float4 out ----
#pragma unroll
    for (int i = 0; i < ROWS_S3 / 1024; ++i) {
        int r = tid + i * 1024;
        int4 a = idx3[2 * r], b = idx3[2 * r + 1];
        uint2 u0 = p2[a.x], u1 = p2[a.y], u2 = p2[a.z], u3 = p2[a.w];
        uint2 u4 = p2[b.x], u5 = p2[b.y], u6 = p2[b.z], u7 = p2[b.w];
        f2 ab = (mk2(bf_lo(u0.x), bf_hi(u0.x)) + mk2(bf_lo(u1.x), bf_hi(u1.x))) +
                (mk2(bf_lo(u2.x), bf_hi(u2.x)) + mk2(bf_lo(u3.x), bf_hi(u3.x)));
        ab = ab + ((mk2(bf_lo(u4.x), bf_hi(u4.x)) + mk2(bf_lo(u5.x), bf_hi(u5.x))) +
                   (mk2(bf_lo(u6.x), bf_hi(u6.x)) + mk2(bf_lo(u7.x), bf_hi(u7.x))));
        f2 cd = (mk2(bf_lo(u0.y), bf_hi(u0.y)) + mk2(bf_lo(u1.y), bf_hi(u1.y))) +
                (mk2(bf_lo(u2.y), bf_hi(u2.y)) + mk2(bf_lo(u3.y), bf_hi(u3.y)));
        cd = cd + ((mk2(bf_lo(u4.y), bf_hi(u4.y)) + mk2(bf_lo(u5.y), bf_hi(u5.y))) +
                   (mk2(bf_lo(u6.y), bf_hi(u6.y)) + mk2(bf_lo(u7.y), bf_hi(u7.y))));
        ab = __builtin_elementwise_max(ab, mk2(1e-37f, 1e-37f));
        cd = __builtin_elementwise_max(cd, mk2(1e-37f, 1e-37f));
        float4 o4;
        o4.x = flog2(ab.x) * LN2;
        o4.y = flog2(ab.y) * LN2;
        o4.z = flog2(cd.x) * LN2;
        o4.w = flog2(cd.y) * LN2;
        // direct transposed store: 16B per lane; line-sharing blocks co-reside per XCD
        reinterpret_cast<float4*>(out)[(size_t)r * (BATCH / 4) + (c0 >> 2)] = o4;
    }
}

extern "C" void kernel_launch(void* const* d_in, const int* in_sizes, int n_in,
                              void* d_out, int out_size, void* d_ws, size_t ws_size,
                              hipStream_t stream) {
    const float* pos  = (const float*)d_in[0];
    const int4*  idx0 = (const int4*)d_in[1];
    const int4*  idx1 = (const int4*)d_in[2];
    const int4*  idx2 = (const int4*)d_in[3];
    const int4*  idx3 = (const int4*)d_in[4];
    float*       out  = (float*)d_out;
    char*        ws   = (char*)d_ws;

    // ws layout: pos_t [4096][1024] (16 MB)
    float* pos_t = (float*)ws;

    // 1) transpose pos [1024][4096] -> pos_t [4096][1024]
    transpose_kernel<<<dim3(BATCH / 32, NVARS / 32), dim3(32, 8), 0, stream>>>(pos, pos_t, NVARS, BATCH);

    // 2) whole circuit in LDS, one block per 4 columns (2 blocks/CU); writes out directly
    pipeline_kernel<<<dim3(BATCH / 4), dim3(1024), 0, stream>>>(pos_t, idx0, idx1, idx2, idx3, out);
}